// Round 13
// baseline (767.673 us; speedup 1.0000x reference)
//
#include <hip/hip_runtime.h>

typedef _Float16 f16;
typedef _Float16 f16x8 __attribute__((ext_vector_type(8)));
typedef float f32x4 __attribute__((ext_vector_type(4)));
typedef unsigned int uint32;
typedef unsigned long long u64;

#define NROWS 65536
#define DDIM  256
#define KCODES 4096
#define THRQ 64u            // 0.25 distance-units * 256 quantization scale
#define MAGIC 12582912.0f   // 1.5 * 2^23
#define LOSS_SCALE 1048576.0f   // 2^20 fixed-point for deterministic loss reduce

// ---- workspace layout (fast path) ----
#define WS_CBT      0               // 2 MB fp16 tiled codebook
#define WS_CNORM    2097152         // 16 KB exact norms
#define WS_CNS      2113536         // 16 KB 256*(cnorm+1024)+MAGIC
#define WS_KEYS     2129920         // 512 KB u64 key per row
#define WS_LIST     2654208         // 256 KB flagged row list (bit31 = full-scan tag)
#define WS_COUNTER  2916352         // 256 B: [0]=flag cnt, +8=u64 lossAcc, [4]=doneCnt
#define WS_PARTIALS 2916608         // 64 KB (fallback path only)
#define WS_NEEDED   2982144

__device__ __forceinline__ void gload_lds16(const void* g, void* l) {
    __builtin_amdgcn_global_load_lds(
        (const __attribute__((address_space(1))) unsigned int*)g,
        (__attribute__((address_space(3))) unsigned int*)l, 16, 0, 0);
}

// insert key k into sorted triple (x1 <= x2 <= x3) of smallest-seen (R7-proven)
__device__ __forceinline__ void ins3(uint32 k, uint32& x1, uint32& x2, uint32& x3) {
    uint32 h1 = max(x1, k); x1 = min(x1, k);
    uint32 h2 = max(x2, h1); x2 = min(x2, h1);
    x3 = min(x3, h2);
}

// ---- tile codebook -> fp16 granules [ct16][kc32][code256] + fused norms + counter reset ----
__global__ void tile_cb_kernel(const float* __restrict__ cb, f16* __restrict__ cbt,
                               float* __restrict__ cnorm, float* __restrict__ cn_s,
                               int* __restrict__ counter) {
    if (blockIdx.x == 0 && threadIdx.x == 0) {
        counter[0] = 0;                       // flag list count
        *(u64*)((char*)counter + 8) = 0ull;   // loss accumulator (fixed-point)
        counter[4] = 0;                       // gather done-counter
    }
    int gid = blockIdx.x * 256 + threadIdx.x;
    int row = gid >> 5, kc = gid & 31;
    const float4* s = (const float4*)(cb + (size_t)row * DDIM + kc * 8);
    float4 a = s[0], b = s[1];
    f16x8 v;
    v[0] = (f16)a.x; v[1] = (f16)a.y; v[2] = (f16)a.z; v[3] = (f16)a.w;
    v[4] = (f16)b.x; v[5] = (f16)b.y; v[6] = (f16)b.z; v[7] = (f16)b.w;
    ((f16x8*)cbt)[((size_t)(row >> 8) * 32 + kc) * 256 + (row & 255)] = v;
    float sq = a.x * a.x + a.y * a.y + a.z * a.z + a.w * a.w
             + b.x * b.x + b.y * b.y + b.z * b.z + b.w * b.w;
    #pragma unroll
    for (int m = 1; m < 32; m <<= 1) sq += __shfl_xor(sq, m);
    if ((threadIdx.x & 31) == 0) {
        cnorm[row] = sq;
        cn_s[row] = 256.f * (sq + 1024.f) + MAGIC;
    }
}

// ---- codebook norms (standalone, fallback path only) ----
__global__ void cnorm_kernel(const float* __restrict__ cb, float* __restrict__ cnorm,
                             float* __restrict__ cn_s, int* __restrict__ counter) {
    if (blockIdx.x == 0 && threadIdx.x == 0) {
        counter[0] = 0;
        *(u64*)((char*)counter + 8) = 0ull;
        counter[4] = 0;
    }
    const int wave = threadIdx.x >> 6;
    const int lane = threadIdx.x & 63;
    const int code = blockIdx.x * 4 + wave;
    const float4 v = *reinterpret_cast<const float4*>(cb + (size_t)code * DDIM + lane * 4);
    float s = v.x * v.x + v.y * v.y + v.z * v.z + v.w * v.w;
    #pragma unroll
    for (int off = 32; off; off >>= 1) s += __shfl_down(s, off);
    if (lane == 0) { cnorm[code] = s; cn_s[code] = 256.f * (s + 1024.f) + MAGIC; }
}

// ---- fused fp16 MFMA GEMM + online argmin (R7/R12 verbatim: proven 190 us) ----
__global__ __launch_bounds__(256, 2) void argmin_mfma(
    const float* __restrict__ z, const f16* __restrict__ cbt,
    const float* __restrict__ cns, u64* __restrict__ keys,
    uint32* __restrict__ list, int* __restrict__ counter)
{
    __shared__ __align__(16) char smem[65536];
    const int tid  = threadIdx.x;
    const int lane = tid & 63;
    const int wid  = tid >> 6;
    const int l15  = lane & 15;
    const int g    = lane >> 4;
    const int row0 = blockIdx.x * 64;

    {   // stage A: 64 rows x K=256, fp32->fp16, granule layout [kc32][r64]
        int kc = tid & 31;
        int rb = tid >> 5;
        #pragma unroll
        for (int it = 0; it < 8; ++it) {
            int r = it * 8 + rb;
            const float4* s = (const float4*)(z + (size_t)(row0 + r) * DDIM + kc * 8);
            float4 a = s[0], b = s[1];
            f16x8 v;
            v[0] = (f16)a.x; v[1] = (f16)a.y; v[2] = (f16)a.z; v[3] = (f16)a.w;
            v[4] = (f16)b.x; v[5] = (f16)b.y; v[6] = (f16)b.z; v[7] = (f16)b.w;
            *(f16x8*)(smem + ((kc * 64 + r) << 4)) = v;
        }
    }
    {   // prologue: stage B step 0 into buf0 (wave-private slices)
        #pragma unroll
        for (int i = 0; i < 4; ++i)
            gload_lds16((const char*)cbt + i * 4096 + wid * 1024 + (lane << 4),
                        smem + 32768 + i * 4096 + wid * 1024);
    }
    __syncthreads();

    uint32 r1[16], r2[16], r3[16];
    #pragma unroll
    for (int i = 0; i < 16; ++i) { r1[i] = 0xFFFFFFFFu; r2[i] = 0xFFFFFFFFu; r3[i] = 0xFFFFFFFFu; }

    #pragma unroll 1
    for (int ct = 0; ct < 16; ++ct) {
        f32x4 acc[4][4];
        #pragma unroll
        for (int i = 0; i < 4; ++i)
            #pragma unroll
            for (int j = 0; j < 4; ++j) acc[i][j] = (f32x4){0.f, 0.f, 0.f, 0.f};

        #pragma unroll
        for (int kw = 0; kw < 8; ++kw) {
            const int s = ct * 8 + kw;
            asm volatile("s_waitcnt lgkmcnt(0)" ::: "memory");
            __builtin_amdgcn_sched_barrier(0);
            if (kw < 7 || ct < 15) {
                const char* src = (const char*)cbt + (size_t)(s + 1) * 16384;
                char* bufn = smem + 32768 + (((kw + 1) & 1) << 14);
                #pragma unroll
                for (int i = 0; i < 4; ++i)
                    gload_lds16(src + i * 4096 + wid * 1024 + (lane << 4),
                                bufn + i * 4096 + wid * 1024);
                asm volatile("s_waitcnt vmcnt(4)" ::: "memory");
            } else {
                asm volatile("s_waitcnt vmcnt(0)" ::: "memory");
            }
            __builtin_amdgcn_sched_barrier(0);

            const char* bufc = smem + 32768 + ((kw & 1) << 14);
            f16x8 a[4], b[4];
            #pragma unroll
            for (int mi = 0; mi < 4; ++mi)
                a[mi] = *(const f16x8*)(smem + (kw * 4 + g) * 1024 + mi * 256 + (l15 << 4));
            #pragma unroll
            for (int ni = 0; ni < 4; ++ni)
                b[ni] = *(const f16x8*)(bufc + g * 4096 + wid * 1024 + ni * 256 + (l15 << 4));
            #pragma unroll
            for (int mi = 0; mi < 4; ++mi)
                #pragma unroll
                for (int ni = 0; ni < 4; ++ni)
                    acc[mi][ni] = __builtin_amdgcn_mfma_f32_16x16x32_f16(a[mi], b[ni], acc[mi][ni], 0, 0, 0);
        }

        const int cbase = ct * 256 + wid * 64 + l15;
        float c0 = cns[cbase], c1 = cns[cbase + 16], c2 = cns[cbase + 32], c3 = cns[cbase + 48];
        #pragma unroll
        for (int mi = 0; mi < 4; ++mi) {
            #pragma unroll
            for (int r = 0; r < 4; ++r) {
                uint32 k0 = (__float_as_uint(fmaf(-512.f, acc[mi][0][r], c0)) << 12) | (uint32)cbase;
                uint32 k1 = (__float_as_uint(fmaf(-512.f, acc[mi][1][r], c1)) << 12) | (uint32)(cbase + 16);
                uint32 k2 = (__float_as_uint(fmaf(-512.f, acc[mi][2][r], c2)) << 12) | (uint32)(cbase + 32);
                uint32 k3 = (__float_as_uint(fmaf(-512.f, acc[mi][3][r], c3)) << 12) | (uint32)(cbase + 48);
                int q = mi * 4 + r;
                ins3(k0, r1[q], r2[q], r3[q]);
                ins3(k1, r1[q], r2[q], r3[q]);
                ins3(k2, r1[q], r2[q], r3[q]);
                ins3(k3, r1[q], r2[q], r3[q]);
            }
        }
    }

    #pragma unroll
    for (int q = 0; q < 16; ++q) {
        uint32 a1 = r1[q], a2 = r2[q], a3 = r3[q];
        #pragma unroll
        for (int m = 1; m < 16; m <<= 1) {
            uint32 o1 = __shfl_xor(a1, m);
            uint32 o2 = __shfl_xor(a2, m);
            uint32 o3 = __shfl_xor(a3, m);
            ins3(o1, a1, a2, a3);
            ins3(o2, a1, a2, a3);
            ins3(o3, a1, a2, a3);
        }
        r1[q] = a1; r2[q] = a2; r3[q] = a3;
    }

    __syncthreads();
    uint4* arr = (uint4*)smem;
    if (l15 == 0) {
        #pragma unroll
        for (int q = 0; q < 16; ++q)
            arr[(wid * 4 + g) * 16 + q] = make_uint4(r1[q], r2[q], r3[q], 0u);
    }
    __syncthreads();
    if (tid < 64) {
        int mi = tid >> 4, gg = (tid >> 2) & 3, r = tid & 3;
        int q = mi * 4 + r;
        uint32 a1 = 0xFFFFFFFFu, a2 = 0xFFFFFFFFu, a3 = 0xFFFFFFFFu;
        #pragma unroll
        for (int w = 0; w < 4; ++w) {
            uint4 v = arr[(w * 4 + gg) * 16 + q];
            ins3(v.x, a1, a2, a3);
            ins3(v.y, a1, a2, a3);
            ins3(v.z, a1, a2, a3);
        }
        int row = row0 + mi * 16 + gg * 4 + r;
        uint32 code1 = a1 & 0xFFFu, code2 = a2 & 0xFFFu;
        uint32 d2 = (a2 >> 12) - (a1 >> 12);
        uint32 d3 = (a3 >> 12) - (a1 >> 12);
        bool full = d3 <= THRQ;
        bool pair = (!full) && (d2 <= THRQ);
        u64 kv = full ? ~0ull
                      : (pair ? (0x8000000000000000ull | ((u64)code2 << 32) | (u64)code1)
                              : (u64)code1);
        keys[row] = kv;
        if (full || pair) {
            int p = atomicAdd(counter, 1);
            list[p] = (uint32)row | (full ? 0x80000000u : 0u);
        }
    }
}

// ---- merged refine: phase 1 = pairwise exact compare, phase 2 = full exact scan ----
// Disjoint row sets; phase-2 loop and its branches are block-uniform, so the
// internal __syncthreads is safe after phase 1's divergent (but converging) loop.
__global__ __launch_bounds__(256) void refine_kernel(
    const float* __restrict__ z, const float* __restrict__ cb,
    const float* __restrict__ cnorm, const uint32* __restrict__ list,
    const int* __restrict__ counter, u64* __restrict__ keys)
{
    __shared__ float zs[256];
    const int tid  = threadIdx.x;
    const int lane = tid & 63;
    const int wid  = tid >> 6;
    const int cnt  = *counter;

    // ---- phase 1: pair rows (one wave each) ----
    {
        const int wv = (blockIdx.x << 2) | wid;
        const int nw = gridDim.x << 2;
        for (int i = wv; i < cnt; i += nw) {
            uint32 e = list[i];
            if (e & 0x80000000u) continue;
            int row = (int)e;
            u64 kv = keys[row];
            int c1 = (int)(kv & 0xFFFull);
            int c2 = (int)((kv >> 32) & 0xFFFull);
            float4 zv = *(const float4*)(z + (size_t)row * DDIM + lane * 4);
            float4 av = *(const float4*)(cb + (size_t)c1 * DDIM + lane * 4);
            float4 bv = *(const float4*)(cb + (size_t)c2 * DDIM + lane * 4);
            float d1 = zv.x * av.x + zv.y * av.y + zv.z * av.z + zv.w * av.w;
            float d2 = zv.x * bv.x + zv.y * bv.y + zv.z * bv.z + zv.w * bv.w;
            #pragma unroll
            for (int off = 32; off; off >>= 1) {
                d1 += __shfl_down(d1, off);
                d2 += __shfl_down(d2, off);
            }
            if (lane == 0) {
                float s1 = fmaf(-2.f, d1, cnorm[c1]);
                float s2 = fmaf(-2.f, d2, cnorm[c2]);
                int w = (s2 < s1 || (s2 == s1 && c2 < c1)) ? c2 : c1;
                keys[row] = (u64)w;
            }
        }
    }

    // ---- phase 2: full-scan rows (8 chunk-blocks per row, coalesced) ----
    const int j = lane & 3;
    const int s = lane >> 2;
    for (int w = blockIdx.x; w < cnt * 8; w += gridDim.x) {
        const int i = w >> 3;
        const int chunk = w & 7;
        uint32 e = list[i];
        if (!(e & 0x80000000u)) continue;   // block-uniform
        const int row = (int)(e & 0x7FFFFFFFu);

        __syncthreads();
        zs[tid] = z[(size_t)row * DDIM + tid];
        __syncthreads();

        float4 zr0 = *(const float4*)&zs[s * 16 + 0];
        float4 zr1 = *(const float4*)&zs[s * 16 + 4];
        float4 zr2 = *(const float4*)&zs[s * 16 + 8];
        float4 zr3 = *(const float4*)&zs[s * 16 + 12];

        u64 best = ~0ull;
        const int cstart = chunk * 512 + wid * 128;
        #pragma unroll 2
        for (int c = cstart; c < cstart + 128; c += 4) {
            const float* p = cb + (size_t)(c + j) * DDIM + s * 16;
            float4 q0 = *(const float4*)(p + 0);
            float4 q1 = *(const float4*)(p + 4);
            float4 q2 = *(const float4*)(p + 8);
            float4 q3 = *(const float4*)(p + 12);
            float d = q0.x * zr0.x + q0.y * zr0.y + q0.z * zr0.z + q0.w * zr0.w;
            d = fmaf(q1.x, zr1.x, d); d = fmaf(q1.y, zr1.y, d);
            d = fmaf(q1.z, zr1.z, d); d = fmaf(q1.w, zr1.w, d);
            d = fmaf(q2.x, zr2.x, d); d = fmaf(q2.y, zr2.y, d);
            d = fmaf(q2.z, zr2.z, d); d = fmaf(q2.w, zr2.w, d);
            d = fmaf(q3.x, zr3.x, d); d = fmaf(q3.y, zr3.y, d);
            d = fmaf(q3.z, zr3.z, d); d = fmaf(q3.w, zr3.w, d);
            d += __shfl_xor(d, 4);
            d += __shfl_xor(d, 8);
            d += __shfl_xor(d, 16);
            d += __shfl_xor(d, 32);
            int code = c + j;
            float v = fmaf(-2.f, d, cnorm[code] + 1024.f);
            u64 key = ((u64)__float_as_uint(v) << 12) | (uint32)code;
            u64 o = __shfl_xor(key, 1); key = o < key ? o : key;
            o = __shfl_xor(key, 2); key = o < key ? o : key;
            best = key < best ? key : best;
        }
        if (lane == 0) atomicMin(&keys[row], best);
    }
}

// ---- gather + straight-through + fused deterministic loss (fixed-point atomics) ----
__global__ void gather_loss_kernel(const float* __restrict__ z, const float* __restrict__ cb,
                                   const u64* __restrict__ keys, float* __restrict__ out,
                                   u64* __restrict__ lossAcc, uint32* __restrict__ doneCnt,
                                   float* __restrict__ out_loss)
{
    const int wave = threadIdx.x >> 6;
    const int lane = threadIdx.x & 63;
    const int row  = blockIdx.x * 4 + wave;
    const int k    = (int)(keys[row] & 0xFFFull);

    const size_t zo = (size_t)row * DDIM + lane * 4;
    float4 zv = *reinterpret_cast<const float4*>(z + zo);
    float4 cv = *reinterpret_cast<const float4*>(cb + (size_t)k * DDIM + lane * 4);
    float4 d;
    d.x = cv.x - zv.x; d.y = cv.y - zv.y; d.z = cv.z - zv.z; d.w = cv.w - zv.w;
    float4 o;
    o.x = zv.x + d.x; o.y = zv.y + d.y; o.z = zv.z + d.z; o.w = zv.w + d.w;
    *reinterpret_cast<float4*>(out + zo) = o;

    float s = d.x * d.x + d.y * d.y + d.z * d.z + d.w * d.w;
    #pragma unroll
    for (int off = 32; off; off >>= 1) s += __shfl_down(s, off);

    __shared__ float ps[4];
    if (lane == 0) ps[wave] = s;
    __syncthreads();
    if (threadIdx.x == 0) {
        float part = (ps[0] + ps[1]) + (ps[2] + ps[3]);
        // exact integer accumulation -> bitwise-deterministic across replays
        u64 q = (u64)(part * LOSS_SCALE + 0.5f);
        u64 old = atomicAdd(lossAcc, q);
        __threadfence();
        uint32 dcnt = atomicAdd(doneCnt, 1u + (uint32)(old & 0ull));  // dep on lossAdd
        if (dcnt == (uint32)(NROWS / 4 - 1)) {
            u64 tot = atomicAdd(lossAcc, 0ull);   // atomic read; all adds ordered
            double m = (double)tot / (double)LOSS_SCALE / 16777216.0;
            out_loss[0] = (float)(0.5 * m);       // BETA*(commit+code) = 0.25*2*mean
        }
    }
}

// ---- fallback: exact fp32 VALU argmin (known-good R1 path, writes u64 keys) ----
#define BM 128
#define BN 128
#define KC 16
#define LDT 132
__global__ __launch_bounds__(256) void argmin_fallback(
    const float* __restrict__ z, const float* __restrict__ cb,
    const float* __restrict__ cnorm, u64* __restrict__ keys)
{
    __shared__ float As[KC][LDT];
    __shared__ float Bs[KC][LDT];
    const int tid  = threadIdx.x;
    const int tx   = tid & 15;
    const int ty   = tid >> 4;
    const int row0 = blockIdx.x * BM;
    const int srow = tid >> 2;
    const int sg   = (tid & 3) * 4;

    float bestv[8]; int besti[8];
    #pragma unroll
    for (int i = 0; i < 8; ++i) { bestv[i] = 3.402823466e38f; besti[i] = 0; }

    for (int ct = 0; ct < KCODES; ct += BN) {
        float acc[8][8];
        #pragma unroll
        for (int i = 0; i < 8; ++i)
            #pragma unroll
            for (int j = 0; j < 8; ++j) acc[i][j] = 0.f;
        for (int kc = 0; kc < DDIM; kc += KC) {
            __syncthreads();
            {
                const float* za = z  + (size_t)(row0 + srow) * DDIM + kc + sg;
                const float* ba = cb + (size_t)(ct   + srow) * DDIM + kc + sg;
                float4 a0 = *reinterpret_cast<const float4*>(za);
                float4 a1 = *reinterpret_cast<const float4*>(za + (size_t)64 * DDIM);
                float4 b0 = *reinterpret_cast<const float4*>(ba);
                float4 b1 = *reinterpret_cast<const float4*>(ba + (size_t)64 * DDIM);
                As[sg + 0][srow] = a0.x; As[sg + 1][srow] = a0.y; As[sg + 2][srow] = a0.z; As[sg + 3][srow] = a0.w;
                As[sg + 0][srow + 64] = a1.x; As[sg + 1][srow + 64] = a1.y; As[sg + 2][srow + 64] = a1.z; As[sg + 3][srow + 64] = a1.w;
                Bs[sg + 0][srow] = b0.x; Bs[sg + 1][srow] = b0.y; Bs[sg + 2][srow] = b0.z; Bs[sg + 3][srow] = b0.w;
                Bs[sg + 0][srow + 64] = b1.x; Bs[sg + 1][srow + 64] = b1.y; Bs[sg + 2][srow + 64] = b1.z; Bs[sg + 3][srow + 64] = b1.w;
            }
            __syncthreads();
            #pragma unroll
            for (int k = 0; k < KC; ++k) {
                float4 a0 = *reinterpret_cast<const float4*>(&As[k][ty * 8]);
                float4 a1 = *reinterpret_cast<const float4*>(&As[k][ty * 8 + 4]);
                float4 b0 = *reinterpret_cast<const float4*>(&Bs[k][tx * 8]);
                float4 b1 = *reinterpret_cast<const float4*>(&Bs[k][tx * 8 + 4]);
                float av[8] = {a0.x, a0.y, a0.z, a0.w, a1.x, a1.y, a1.z, a1.w};
                float bv[8] = {b0.x, b0.y, b0.z, b0.w, b1.x, b1.y, b1.z, b1.w};
                #pragma unroll
                for (int i = 0; i < 8; ++i)
                    #pragma unroll
                    for (int j = 0; j < 8; ++j)
                        acc[i][j] = fmaf(av[i], bv[j], acc[i][j]);
            }
        }
        float cn[8];
        float4 c0v = *reinterpret_cast<const float4*>(cnorm + ct + tx * 8);
        float4 c1v = *reinterpret_cast<const float4*>(cnorm + ct + tx * 8 + 4);
        cn[0] = c0v.x; cn[1] = c0v.y; cn[2] = c0v.z; cn[3] = c0v.w;
        cn[4] = c1v.x; cn[5] = c1v.y; cn[6] = c1v.z; cn[7] = c1v.w;
        #pragma unroll
        for (int i = 0; i < 8; ++i) {
            float v = fmaf(-2.f, acc[i][0], cn[0]);
            int ix = ct + tx * 8;
            #pragma unroll
            for (int j = 1; j < 8; ++j) {
                float t = fmaf(-2.f, acc[i][j], cn[j]);
                if (t < v) { v = t; ix = ct + tx * 8 + j; }
            }
            #pragma unroll
            for (int m = 1; m < 16; m <<= 1) {
                float ov = __shfl_xor(v, m);
                int oi = __shfl_xor(ix, m);
                if (ov < v || (ov == v && oi < ix)) { v = ov; ix = oi; }
            }
            if (v < bestv[i] || (v == bestv[i] && ix < besti[i])) { bestv[i] = v; besti[i] = ix; }
        }
    }
    if (tx == 0) {
        #pragma unroll
        for (int i = 0; i < 8; ++i) keys[row0 + ty * 8 + i] = (u64)besti[i];
    }
}

extern "C" void kernel_launch(void* const* d_in, const int* in_sizes, int n_in,
                              void* d_out, int out_size, void* d_ws, size_t ws_size,
                              hipStream_t stream)
{
    const float* z  = (const float*)d_in[0];
    const float* cb = (const float*)d_in[1];
    float* out = (float*)d_out;
    char* wsb = (char*)d_ws;

    if (ws_size >= WS_NEEDED) {
        f16*    cbt      = (f16*)(wsb + WS_CBT);
        float*  cnorm    = (float*)(wsb + WS_CNORM);
        float*  cn_s     = (float*)(wsb + WS_CNS);
        u64*    keys     = (u64*)(wsb + WS_KEYS);
        uint32* list     = (uint32*)(wsb + WS_LIST);
        int*    counter  = (int*)(wsb + WS_COUNTER);
        u64*    lossAcc  = (u64*)(wsb + WS_COUNTER + 8);
        uint32* doneCnt  = (uint32*)(wsb + WS_COUNTER + 16);

        tile_cb_kernel<<<512, 256, 0, stream>>>(cb, cbt, cnorm, cn_s, counter);
        argmin_mfma<<<NROWS / 64, 256, 0, stream>>>(z, cbt, cn_s, keys, list, counter);
        refine_kernel<<<2048, 256, 0, stream>>>(z, cb, cnorm, list, counter, keys);
        gather_loss_kernel<<<NROWS / 4, 256, 0, stream>>>(z, cb, keys, out, lossAcc, doneCnt,
                                                          out + (size_t)NROWS * DDIM);
    } else {
        u64*    keys     = (u64*)(wsb + 0);
        float*  cnorm    = (float*)(wsb + 524288);
        float*  cn_s     = (float*)(wsb + 540672);
        int*    counter  = (int*)(wsb + 557056);
        u64*    lossAcc  = (u64*)(wsb + 557064);
        uint32* doneCnt  = (uint32*)(wsb + 557072);

        cnorm_kernel<<<KCODES / 4, 256, 0, stream>>>(cb, cnorm, cn_s, counter);
        argmin_fallback<<<NROWS / BM, 256, 0, stream>>>(z, cb, cnorm, keys);
        gather_loss_kernel<<<NROWS / 4, 256, 0, stream>>>(z, cb, keys, out, lossAcc, doneCnt,
                                                          out + (size_t)NROWS * DDIM);
    }
}

// Round 14
// 297.869 us; speedup vs baseline: 2.5772x; 2.5772x over previous
//
#include <hip/hip_runtime.h>

typedef _Float16 f16;
typedef _Float16 f16x8 __attribute__((ext_vector_type(8)));
typedef float f32x4 __attribute__((ext_vector_type(4)));
typedef unsigned int uint32;
typedef unsigned long long u64;

#define NROWS 65536
#define DDIM  256
#define KCODES 4096
#define THRQ 64u            // 0.25 distance-units * 256 quantization scale
#define MAGIC 12582912.0f   // 1.5 * 2^23

// ---- workspace layout (fast path) ----
#define WS_CBT      0               // 2 MB fp16 tiled codebook
#define WS_CNORM    2097152         // 16 KB exact norms
#define WS_CNS      2113536         // 16 KB 256*(cnorm+1024)+MAGIC
#define WS_KEYS     2129920         // 512 KB u64 key per row
#define WS_LIST     2654208         // 256 KB flagged row list (bit31 = full-scan tag)
#define WS_COUNTER  2916352         // 256 B
#define WS_PARTIALS 2916608         // 64 KB
#define WS_NEEDED   2982144

__device__ __forceinline__ void gload_lds16(const void* g, void* l) {
    __builtin_amdgcn_global_load_lds(
        (const __attribute__((address_space(1))) unsigned int*)g,
        (__attribute__((address_space(3))) unsigned int*)l, 16, 0, 0);
}

// insert key k into sorted triple (x1 <= x2 <= x3) of smallest-seen (R7-proven)
__device__ __forceinline__ void ins3(uint32 k, uint32& x1, uint32& x2, uint32& x3) {
    uint32 h1 = max(x1, k); x1 = min(x1, k);
    uint32 h2 = max(x2, h1); x2 = min(x2, h1);
    x3 = min(x3, h2);
}

// ---- tile codebook -> fp16 granules [ct16][kc32][code256] + fused norms + counter reset ----
__global__ void tile_cb_kernel(const float* __restrict__ cb, f16* __restrict__ cbt,
                               float* __restrict__ cnorm, float* __restrict__ cn_s,
                               int* __restrict__ counter) {
    if (blockIdx.x == 0 && threadIdx.x == 0) counter[0] = 0;
    int gid = blockIdx.x * 256 + threadIdx.x;
    int row = gid >> 5, kc = gid & 31;
    const float4* s = (const float4*)(cb + (size_t)row * DDIM + kc * 8);
    float4 a = s[0], b = s[1];
    f16x8 v;
    v[0] = (f16)a.x; v[1] = (f16)a.y; v[2] = (f16)a.z; v[3] = (f16)a.w;
    v[4] = (f16)b.x; v[5] = (f16)b.y; v[6] = (f16)b.z; v[7] = (f16)b.w;
    ((f16x8*)cbt)[((size_t)(row >> 8) * 32 + kc) * 256 + (row & 255)] = v;
    float sq = a.x * a.x + a.y * a.y + a.z * a.z + a.w * a.w
             + b.x * b.x + b.y * b.y + b.z * b.z + b.w * b.w;
    #pragma unroll
    for (int m = 1; m < 32; m <<= 1) sq += __shfl_xor(sq, m);
    if ((threadIdx.x & 31) == 0) {
        cnorm[row] = sq;
        cn_s[row] = 256.f * (sq + 1024.f) + MAGIC;
    }
}

// ---- codebook norms (standalone, fallback path only) ----
__global__ void cnorm_kernel(const float* __restrict__ cb, float* __restrict__ cnorm,
                             float* __restrict__ cn_s, int* __restrict__ counter) {
    if (blockIdx.x == 0 && threadIdx.x == 0) counter[0] = 0;
    const int wave = threadIdx.x >> 6;
    const int lane = threadIdx.x & 63;
    const int code = blockIdx.x * 4 + wave;
    const float4 v = *reinterpret_cast<const float4*>(cb + (size_t)code * DDIM + lane * 4);
    float s = v.x * v.x + v.y * v.y + v.z * v.z + v.w * v.w;
    #pragma unroll
    for (int off = 32; off; off >>= 1) s += __shfl_down(s, off);
    if (lane == 0) { cnorm[code] = s; cn_s[code] = 256.f * (s + 1024.f) + MAGIC; }
}

// ---- fused fp16 MFMA GEMM + online argmin (R7/R12 verbatim: proven 190 us) ----
__global__ __launch_bounds__(256, 2) void argmin_mfma(
    const float* __restrict__ z, const f16* __restrict__ cbt,
    const float* __restrict__ cns, u64* __restrict__ keys,
    uint32* __restrict__ list, int* __restrict__ counter)
{
    __shared__ __align__(16) char smem[65536];
    const int tid  = threadIdx.x;
    const int lane = tid & 63;
    const int wid  = tid >> 6;
    const int l15  = lane & 15;
    const int g    = lane >> 4;
    const int row0 = blockIdx.x * 64;

    {   // stage A: 64 rows x K=256, fp32->fp16, granule layout [kc32][r64]
        int kc = tid & 31;
        int rb = tid >> 5;
        #pragma unroll
        for (int it = 0; it < 8; ++it) {
            int r = it * 8 + rb;
            const float4* s = (const float4*)(z + (size_t)(row0 + r) * DDIM + kc * 8);
            float4 a = s[0], b = s[1];
            f16x8 v;
            v[0] = (f16)a.x; v[1] = (f16)a.y; v[2] = (f16)a.z; v[3] = (f16)a.w;
            v[4] = (f16)b.x; v[5] = (f16)b.y; v[6] = (f16)b.z; v[7] = (f16)b.w;
            *(f16x8*)(smem + ((kc * 64 + r) << 4)) = v;
        }
    }
    {   // prologue: stage B step 0 into buf0 (wave-private slices)
        #pragma unroll
        for (int i = 0; i < 4; ++i)
            gload_lds16((const char*)cbt + i * 4096 + wid * 1024 + (lane << 4),
                        smem + 32768 + i * 4096 + wid * 1024);
    }
    __syncthreads();

    uint32 r1[16], r2[16], r3[16];
    #pragma unroll
    for (int i = 0; i < 16; ++i) { r1[i] = 0xFFFFFFFFu; r2[i] = 0xFFFFFFFFu; r3[i] = 0xFFFFFFFFu; }

    #pragma unroll 1
    for (int ct = 0; ct < 16; ++ct) {
        f32x4 acc[4][4];
        #pragma unroll
        for (int i = 0; i < 4; ++i)
            #pragma unroll
            for (int j = 0; j < 4; ++j) acc[i][j] = (f32x4){0.f, 0.f, 0.f, 0.f};

        #pragma unroll
        for (int kw = 0; kw < 8; ++kw) {
            const int s = ct * 8 + kw;
            asm volatile("s_waitcnt lgkmcnt(0)" ::: "memory");
            __builtin_amdgcn_sched_barrier(0);
            if (kw < 7 || ct < 15) {
                const char* src = (const char*)cbt + (size_t)(s + 1) * 16384;
                char* bufn = smem + 32768 + (((kw + 1) & 1) << 14);
                #pragma unroll
                for (int i = 0; i < 4; ++i)
                    gload_lds16(src + i * 4096 + wid * 1024 + (lane << 4),
                                bufn + i * 4096 + wid * 1024);
                asm volatile("s_waitcnt vmcnt(4)" ::: "memory");
            } else {
                asm volatile("s_waitcnt vmcnt(0)" ::: "memory");
            }
            __builtin_amdgcn_sched_barrier(0);

            const char* bufc = smem + 32768 + ((kw & 1) << 14);
            f16x8 a[4], b[4];
            #pragma unroll
            for (int mi = 0; mi < 4; ++mi)
                a[mi] = *(const f16x8*)(smem + (kw * 4 + g) * 1024 + mi * 256 + (l15 << 4));
            #pragma unroll
            for (int ni = 0; ni < 4; ++ni)
                b[ni] = *(const f16x8*)(bufc + g * 4096 + wid * 1024 + ni * 256 + (l15 << 4));
            #pragma unroll
            for (int mi = 0; mi < 4; ++mi)
                #pragma unroll
                for (int ni = 0; ni < 4; ++ni)
                    acc[mi][ni] = __builtin_amdgcn_mfma_f32_16x16x32_f16(a[mi], b[ni], acc[mi][ni], 0, 0, 0);
        }

        const int cbase = ct * 256 + wid * 64 + l15;
        float c0 = cns[cbase], c1 = cns[cbase + 16], c2 = cns[cbase + 32], c3 = cns[cbase + 48];
        #pragma unroll
        for (int mi = 0; mi < 4; ++mi) {
            #pragma unroll
            for (int r = 0; r < 4; ++r) {
                uint32 k0 = (__float_as_uint(fmaf(-512.f, acc[mi][0][r], c0)) << 12) | (uint32)cbase;
                uint32 k1 = (__float_as_uint(fmaf(-512.f, acc[mi][1][r], c1)) << 12) | (uint32)(cbase + 16);
                uint32 k2 = (__float_as_uint(fmaf(-512.f, acc[mi][2][r], c2)) << 12) | (uint32)(cbase + 32);
                uint32 k3 = (__float_as_uint(fmaf(-512.f, acc[mi][3][r], c3)) << 12) | (uint32)(cbase + 48);
                int q = mi * 4 + r;
                ins3(k0, r1[q], r2[q], r3[q]);
                ins3(k1, r1[q], r2[q], r3[q]);
                ins3(k2, r1[q], r2[q], r3[q]);
                ins3(k3, r1[q], r2[q], r3[q]);
            }
        }
    }

    #pragma unroll
    for (int q = 0; q < 16; ++q) {
        uint32 a1 = r1[q], a2 = r2[q], a3 = r3[q];
        #pragma unroll
        for (int m = 1; m < 16; m <<= 1) {
            uint32 o1 = __shfl_xor(a1, m);
            uint32 o2 = __shfl_xor(a2, m);
            uint32 o3 = __shfl_xor(a3, m);
            ins3(o1, a1, a2, a3);
            ins3(o2, a1, a2, a3);
            ins3(o3, a1, a2, a3);
        }
        r1[q] = a1; r2[q] = a2; r3[q] = a3;
    }

    __syncthreads();
    uint4* arr = (uint4*)smem;
    if (l15 == 0) {
        #pragma unroll
        for (int q = 0; q < 16; ++q)
            arr[(wid * 4 + g) * 16 + q] = make_uint4(r1[q], r2[q], r3[q], 0u);
    }
    __syncthreads();
    if (tid < 64) {
        int mi = tid >> 4, gg = (tid >> 2) & 3, r = tid & 3;
        int q = mi * 4 + r;
        uint32 a1 = 0xFFFFFFFFu, a2 = 0xFFFFFFFFu, a3 = 0xFFFFFFFFu;
        #pragma unroll
        for (int w = 0; w < 4; ++w) {
            uint4 v = arr[(w * 4 + gg) * 16 + q];
            ins3(v.x, a1, a2, a3);
            ins3(v.y, a1, a2, a3);
            ins3(v.z, a1, a2, a3);
        }
        int row = row0 + mi * 16 + gg * 4 + r;
        uint32 code1 = a1 & 0xFFFu, code2 = a2 & 0xFFFu;
        uint32 d2 = (a2 >> 12) - (a1 >> 12);
        uint32 d3 = (a3 >> 12) - (a1 >> 12);
        bool full = d3 <= THRQ;
        bool pair = (!full) && (d2 <= THRQ);
        u64 kv = full ? ~0ull
                      : (pair ? (0x8000000000000000ull | ((u64)code2 << 32) | (u64)code1)
                              : (u64)code1);
        keys[row] = kv;
        if (full || pair) {
            int p = atomicAdd(counter, 1);
            list[p] = (uint32)row | (full ? 0x80000000u : 0u);
        }
    }
}

// ---- merged refine: phase 1 = pairwise exact compare, phase 2 = full exact scan ----
// (R13-proven correct; disjoint row sets, phase-2 branches block-uniform)
__global__ __launch_bounds__(256) void refine_kernel(
    const float* __restrict__ z, const float* __restrict__ cb,
    const float* __restrict__ cnorm, const uint32* __restrict__ list,
    const int* __restrict__ counter, u64* __restrict__ keys)
{
    __shared__ float zs[256];
    const int tid  = threadIdx.x;
    const int lane = tid & 63;
    const int wid  = tid >> 6;
    const int cnt  = *counter;

    // ---- phase 1: pair rows (one wave each) ----
    {
        const int wv = (blockIdx.x << 2) | wid;
        const int nw = gridDim.x << 2;
        for (int i = wv; i < cnt; i += nw) {
            uint32 e = list[i];
            if (e & 0x80000000u) continue;
            int row = (int)e;
            u64 kv = keys[row];
            int c1 = (int)(kv & 0xFFFull);
            int c2 = (int)((kv >> 32) & 0xFFFull);
            float4 zv = *(const float4*)(z + (size_t)row * DDIM + lane * 4);
            float4 av = *(const float4*)(cb + (size_t)c1 * DDIM + lane * 4);
            float4 bv = *(const float4*)(cb + (size_t)c2 * DDIM + lane * 4);
            float d1 = zv.x * av.x + zv.y * av.y + zv.z * av.z + zv.w * av.w;
            float d2 = zv.x * bv.x + zv.y * bv.y + zv.z * bv.z + zv.w * bv.w;
            #pragma unroll
            for (int off = 32; off; off >>= 1) {
                d1 += __shfl_down(d1, off);
                d2 += __shfl_down(d2, off);
            }
            if (lane == 0) {
                float s1 = fmaf(-2.f, d1, cnorm[c1]);
                float s2 = fmaf(-2.f, d2, cnorm[c2]);
                int w = (s2 < s1 || (s2 == s1 && c2 < c1)) ? c2 : c1;
                keys[row] = (u64)w;
            }
        }
    }

    // ---- phase 2: full-scan rows (8 chunk-blocks per row, coalesced) ----
    const int j = lane & 3;
    const int s = lane >> 2;
    for (int w = blockIdx.x; w < cnt * 8; w += gridDim.x) {
        const int i = w >> 3;
        const int chunk = w & 7;
        uint32 e = list[i];
        if (!(e & 0x80000000u)) continue;   // block-uniform
        const int row = (int)(e & 0x7FFFFFFFu);

        __syncthreads();
        zs[tid] = z[(size_t)row * DDIM + tid];
        __syncthreads();

        float4 zr0 = *(const float4*)&zs[s * 16 + 0];
        float4 zr1 = *(const float4*)&zs[s * 16 + 4];
        float4 zr2 = *(const float4*)&zs[s * 16 + 8];
        float4 zr3 = *(const float4*)&zs[s * 16 + 12];

        u64 best = ~0ull;
        const int cstart = chunk * 512 + wid * 128;
        #pragma unroll 2
        for (int c = cstart; c < cstart + 128; c += 4) {
            const float* p = cb + (size_t)(c + j) * DDIM + s * 16;
            float4 q0 = *(const float4*)(p + 0);
            float4 q1 = *(const float4*)(p + 4);
            float4 q2 = *(const float4*)(p + 8);
            float4 q3 = *(const float4*)(p + 12);
            float d = q0.x * zr0.x + q0.y * zr0.y + q0.z * zr0.z + q0.w * zr0.w;
            d = fmaf(q1.x, zr1.x, d); d = fmaf(q1.y, zr1.y, d);
            d = fmaf(q1.z, zr1.z, d); d = fmaf(q1.w, zr1.w, d);
            d = fmaf(q2.x, zr2.x, d); d = fmaf(q2.y, zr2.y, d);
            d = fmaf(q2.z, zr2.z, d); d = fmaf(q2.w, zr2.w, d);
            d = fmaf(q3.x, zr3.x, d); d = fmaf(q3.y, zr3.y, d);
            d = fmaf(q3.z, zr3.z, d); d = fmaf(q3.w, zr3.w, d);
            d += __shfl_xor(d, 4);
            d += __shfl_xor(d, 8);
            d += __shfl_xor(d, 16);
            d += __shfl_xor(d, 32);
            int code = c + j;
            float v = fmaf(-2.f, d, cnorm[code] + 1024.f);
            u64 key = ((u64)__float_as_uint(v) << 12) | (uint32)code;
            u64 o = __shfl_xor(key, 1); key = o < key ? o : key;
            o = __shfl_xor(key, 2); key = o < key ? o : key;
            best = key < best ? key : best;
        }
        if (lane == 0) atomicMin(&keys[row], best);
    }
}

// ---- gather + straight-through + loss partials (R12-proven: no atomics, no fences) ----
__global__ void gather_loss_kernel(const float* __restrict__ z, const float* __restrict__ cb,
                                   const u64* __restrict__ keys, float* __restrict__ out,
                                   float* __restrict__ partials)
{
    const int wave = threadIdx.x >> 6;
    const int lane = threadIdx.x & 63;
    const int row  = blockIdx.x * 4 + wave;
    const int k    = (int)(keys[row] & 0xFFFull);

    const size_t zo = (size_t)row * DDIM + lane * 4;
    float4 zv = *reinterpret_cast<const float4*>(z + zo);
    float4 cv = *reinterpret_cast<const float4*>(cb + (size_t)k * DDIM + lane * 4);
    float4 d;
    d.x = cv.x - zv.x; d.y = cv.y - zv.y; d.z = cv.z - zv.z; d.w = cv.w - zv.w;
    float4 o;
    o.x = zv.x + d.x; o.y = zv.y + d.y; o.z = zv.z + d.z; o.w = zv.w + d.w;
    *reinterpret_cast<float4*>(out + zo) = o;

    float s = d.x * d.x + d.y * d.y + d.z * d.z + d.w * d.w;
    #pragma unroll
    for (int off = 32; off; off >>= 1) s += __shfl_down(s, off);

    __shared__ float ps[4];
    if (lane == 0) ps[wave] = s;
    __syncthreads();
    if (threadIdx.x == 0) partials[blockIdx.x] = (ps[0] + ps[1]) + (ps[2] + ps[3]);
}

__global__ void finalize_kernel(const float* __restrict__ partials, float* __restrict__ out_loss)
{
    float s = 0.f;
    for (int i = threadIdx.x; i < 16384; i += 256) s += partials[i];
    #pragma unroll
    for (int off = 32; off; off >>= 1) s += __shfl_down(s, off);
    __shared__ float ws_[4];
    if ((threadIdx.x & 63) == 0) ws_[threadIdx.x >> 6] = s;
    __syncthreads();
    if (threadIdx.x == 0) {
        float t = (ws_[0] + ws_[1]) + (ws_[2] + ws_[3]);
        float m = t / 16777216.f;
        out_loss[0] = 0.25f * (m + m);
    }
}

// ---- fallback: exact fp32 VALU argmin (known-good R1 path, writes u64 keys) ----
#define BM 128
#define BN 128
#define KC 16
#define LDT 132
__global__ __launch_bounds__(256) void argmin_fallback(
    const float* __restrict__ z, const float* __restrict__ cb,
    const float* __restrict__ cnorm, u64* __restrict__ keys)
{
    __shared__ float As[KC][LDT];
    __shared__ float Bs[KC][LDT];
    const int tid  = threadIdx.x;
    const int tx   = tid & 15;
    const int ty   = tid >> 4;
    const int row0 = blockIdx.x * BM;
    const int srow = tid >> 2;
    const int sg   = (tid & 3) * 4;

    float bestv[8]; int besti[8];
    #pragma unroll
    for (int i = 0; i < 8; ++i) { bestv[i] = 3.402823466e38f; besti[i] = 0; }

    for (int ct = 0; ct < KCODES; ct += BN) {
        float acc[8][8];
        #pragma unroll
        for (int i = 0; i < 8; ++i)
            #pragma unroll
            for (int j = 0; j < 8; ++j) acc[i][j] = 0.f;
        for (int kc = 0; kc < DDIM; kc += KC) {
            __syncthreads();
            {
                const float* za = z  + (size_t)(row0 + srow) * DDIM + kc + sg;
                const float* ba = cb + (size_t)(ct   + srow) * DDIM + kc + sg;
                float4 a0 = *reinterpret_cast<const float4*>(za);
                float4 a1 = *reinterpret_cast<const float4*>(za + (size_t)64 * DDIM);
                float4 b0 = *reinterpret_cast<const float4*>(ba);
                float4 b1 = *reinterpret_cast<const float4*>(ba + (size_t)64 * DDIM);
                As[sg + 0][srow] = a0.x; As[sg + 1][srow] = a0.y; As[sg + 2][srow] = a0.z; As[sg + 3][srow] = a0.w;
                As[sg + 0][srow + 64] = a1.x; As[sg + 1][srow + 64] = a1.y; As[sg + 2][srow + 64] = a1.z; As[sg + 3][srow + 64] = a1.w;
                Bs[sg + 0][srow] = b0.x; Bs[sg + 1][srow] = b0.y; Bs[sg + 2][srow] = b0.z; Bs[sg + 3][srow] = b0.w;
                Bs[sg + 0][srow + 64] = b1.x; Bs[sg + 1][srow + 64] = b1.y; Bs[sg + 2][srow + 64] = b1.z; Bs[sg + 3][srow + 64] = b1.w;
            }
            __syncthreads();
            #pragma unroll
            for (int k = 0; k < KC; ++k) {
                float4 a0 = *reinterpret_cast<const float4*>(&As[k][ty * 8]);
                float4 a1 = *reinterpret_cast<const float4*>(&As[k][ty * 8 + 4]);
                float4 b0 = *reinterpret_cast<const float4*>(&Bs[k][tx * 8]);
                float4 b1 = *reinterpret_cast<const float4*>(&Bs[k][tx * 8 + 4]);
                float av[8] = {a0.x, a0.y, a0.z, a0.w, a1.x, a1.y, a1.z, a1.w};
                float bv[8] = {b0.x, b0.y, b0.z, b0.w, b1.x, b1.y, b1.z, b1.w};
                #pragma unroll
                for (int i = 0; i < 8; ++i)
                    #pragma unroll
                    for (int j = 0; j < 8; ++j)
                        acc[i][j] = fmaf(av[i], bv[j], acc[i][j]);
            }
        }
        float cn[8];
        float4 c0v = *reinterpret_cast<const float4*>(cnorm + ct + tx * 8);
        float4 c1v = *reinterpret_cast<const float4*>(cnorm + ct + tx * 8 + 4);
        cn[0] = c0v.x; cn[1] = c0v.y; cn[2] = c0v.z; cn[3] = c0v.w;
        cn[4] = c1v.x; cn[5] = c1v.y; cn[6] = c1v.z; cn[7] = c1v.w;
        #pragma unroll
        for (int i = 0; i < 8; ++i) {
            float v = fmaf(-2.f, acc[i][0], cn[0]);
            int ix = ct + tx * 8;
            #pragma unroll
            for (int j = 1; j < 8; ++j) {
                float t = fmaf(-2.f, acc[i][j], cn[j]);
                if (t < v) { v = t; ix = ct + tx * 8 + j; }
            }
            #pragma unroll
            for (int m = 1; m < 16; m <<= 1) {
                float ov = __shfl_xor(v, m);
                int oi = __shfl_xor(ix, m);
                if (ov < v || (ov == v && oi < ix)) { v = ov; ix = oi; }
            }
            if (v < bestv[i] || (v == bestv[i] && ix < besti[i])) { bestv[i] = v; besti[i] = ix; }
        }
    }
    if (tx == 0) {
        #pragma unroll
        for (int i = 0; i < 8; ++i) keys[row0 + ty * 8 + i] = (u64)besti[i];
    }
}

extern "C" void kernel_launch(void* const* d_in, const int* in_sizes, int n_in,
                              void* d_out, int out_size, void* d_ws, size_t ws_size,
                              hipStream_t stream)
{
    const float* z  = (const float*)d_in[0];
    const float* cb = (const float*)d_in[1];
    float* out = (float*)d_out;
    char* wsb = (char*)d_ws;

    if (ws_size >= WS_NEEDED) {
        f16*    cbt      = (f16*)(wsb + WS_CBT);
        float*  cnorm    = (float*)(wsb + WS_CNORM);
        float*  cn_s     = (float*)(wsb + WS_CNS);
        u64*    keys     = (u64*)(wsb + WS_KEYS);
        uint32* list     = (uint32*)(wsb + WS_LIST);
        int*    counter  = (int*)(wsb + WS_COUNTER);
        float*  partials = (float*)(wsb + WS_PARTIALS);

        tile_cb_kernel<<<512, 256, 0, stream>>>(cb, cbt, cnorm, cn_s, counter);
        argmin_mfma<<<NROWS / 64, 256, 0, stream>>>(z, cbt, cn_s, keys, list, counter);
        refine_kernel<<<2048, 256, 0, stream>>>(z, cb, cnorm, list, counter, keys);
        gather_loss_kernel<<<NROWS / 4, 256, 0, stream>>>(z, cb, keys, out, partials);
        finalize_kernel<<<1, 256, 0, stream>>>(partials, out + (size_t)NROWS * DDIM);
    } else {
        u64*   keys     = (u64*)(wsb + 0);
        float* cnorm    = (float*)(wsb + 524288);
        float* cn_s     = (float*)(wsb + 540672);
        float* partials = (float*)(wsb + 557056);
        int*   counter  = (int*)(wsb + 622592);

        cnorm_kernel<<<KCODES / 4, 256, 0, stream>>>(cb, cnorm, cn_s, counter);
        argmin_fallback<<<NROWS / BM, 256, 0, stream>>>(z, cb, cnorm, keys);
        gather_loss_kernel<<<NROWS / 4, 256, 0, stream>>>(z, cb, keys, out, partials);
        finalize_kernel<<<1, 256, 0, stream>>>(partials, out + (size_t)NROWS * DDIM);
    }
}

// Round 15
// 290.312 us; speedup vs baseline: 2.6443x; 1.0260x over previous
//
#include <hip/hip_runtime.h>

typedef _Float16 f16;
typedef _Float16 f16x8 __attribute__((ext_vector_type(8)));
typedef float f32x4 __attribute__((ext_vector_type(4)));
typedef unsigned int uint32;
typedef unsigned long long u64;

#define NROWS 65536
#define DDIM  256
#define KCODES 4096
#define THRQ 64u            // 0.25 distance-units * 256 quantization scale
#define MAGIC 12582912.0f   // 1.5 * 2^23

// ---- workspace layout (fast path) ----
#define WS_CBT      0               // 2 MB fp16 tiled codebook
#define WS_CNORM    2097152         // 16 KB exact norms
#define WS_CNS      2113536         // 16 KB 256*(cnorm+1024)+MAGIC
#define WS_KEYS     2129920         // 512 KB u64 key per row
#define WS_LIST     2654208         // 256 KB flagged row list (bit31 = full-scan tag)
#define WS_COUNTER  2916352         // 256 B
#define WS_PARTIALS 2916608         // 64 KB
#define WS_NEEDED   2982144

__device__ __forceinline__ void gload_lds16(const void* g, void* l) {
    __builtin_amdgcn_global_load_lds(
        (const __attribute__((address_space(1))) unsigned int*)g,
        (__attribute__((address_space(3))) unsigned int*)l, 16, 0, 0);
}

// 3-input unsigned median (single VALU op; R10/R11-validated)
__device__ __forceinline__ uint32 med3u(uint32 a, uint32 b, uint32 c) {
    uint32 d;
    asm("v_med3_u32 %0, %1, %2, %3" : "=v"(d) : "v"(a), "v"(b), "v"(c));
    return d;
}
// insert key k into sorted triple (x1 <= x2 <= x3): 3 ops (2 med3 + 1 min)
// case-verified: k<=x2 -> (min,x1|k order, x2); x2<k<=x3 -> k third; k>x3 -> unchanged third
__device__ __forceinline__ void ins3(uint32 k, uint32& x1, uint32& x2, uint32& x3) {
    uint32 y3 = med3u(x2, k, x3);
    uint32 y2 = med3u(x1, k, x2);
    x1 = min(x1, k);
    x2 = y2; x3 = y3;
}

// ---- tile codebook -> fp16 granules [ct16][kc32][code256] + fused norms + counter reset ----
__global__ void tile_cb_kernel(const float* __restrict__ cb, f16* __restrict__ cbt,
                               float* __restrict__ cnorm, float* __restrict__ cn_s,
                               int* __restrict__ counter) {
    if (blockIdx.x == 0 && threadIdx.x == 0) counter[0] = 0;
    int gid = blockIdx.x * 256 + threadIdx.x;
    int row = gid >> 5, kc = gid & 31;
    const float4* s = (const float4*)(cb + (size_t)row * DDIM + kc * 8);
    float4 a = s[0], b = s[1];
    f16x8 v;
    v[0] = (f16)a.x; v[1] = (f16)a.y; v[2] = (f16)a.z; v[3] = (f16)a.w;
    v[4] = (f16)b.x; v[5] = (f16)b.y; v[6] = (f16)b.z; v[7] = (f16)b.w;
    ((f16x8*)cbt)[((size_t)(row >> 8) * 32 + kc) * 256 + (row & 255)] = v;
    float sq = a.x * a.x + a.y * a.y + a.z * a.z + a.w * a.w
             + b.x * b.x + b.y * b.y + b.z * b.z + b.w * b.w;
    #pragma unroll
    for (int m = 1; m < 32; m <<= 1) sq += __shfl_xor(sq, m);
    if ((threadIdx.x & 31) == 0) {
        cnorm[row] = sq;
        cn_s[row] = 256.f * (sq + 1024.f) + MAGIC;
    }
}

// ---- codebook norms (standalone, fallback path only) ----
__global__ void cnorm_kernel(const float* __restrict__ cb, float* __restrict__ cnorm,
                             float* __restrict__ cn_s, int* __restrict__ counter) {
    if (blockIdx.x == 0 && threadIdx.x == 0) counter[0] = 0;
    const int wave = threadIdx.x >> 6;
    const int lane = threadIdx.x & 63;
    const int code = blockIdx.x * 4 + wave;
    const float4 v = *reinterpret_cast<const float4*>(cb + (size_t)code * DDIM + lane * 4);
    float s = v.x * v.x + v.y * v.y + v.z * v.z + v.w * v.w;
    #pragma unroll
    for (int off = 32; off; off >>= 1) s += __shfl_down(s, off);
    if (lane == 0) { cnorm[code] = s; cn_s[code] = 256.f * (s + 1024.f) + MAGIC; }
}

// ---- fused fp16 MFMA GEMM + online argmin (R7 structure + med3-ins3 + T5 setprio) ----
__global__ __launch_bounds__(256, 2) void argmin_mfma(
    const float* __restrict__ z, const f16* __restrict__ cbt,
    const float* __restrict__ cns, u64* __restrict__ keys,
    uint32* __restrict__ list, int* __restrict__ counter)
{
    __shared__ __align__(16) char smem[65536];
    const int tid  = threadIdx.x;
    const int lane = tid & 63;
    const int wid  = tid >> 6;
    const int l15  = lane & 15;
    const int g    = lane >> 4;
    const int row0 = blockIdx.x * 64;

    {   // stage A: 64 rows x K=256, fp32->fp16, granule layout [kc32][r64]
        int kc = tid & 31;
        int rb = tid >> 5;
        #pragma unroll
        for (int it = 0; it < 8; ++it) {
            int r = it * 8 + rb;
            const float4* s = (const float4*)(z + (size_t)(row0 + r) * DDIM + kc * 8);
            float4 a = s[0], b = s[1];
            f16x8 v;
            v[0] = (f16)a.x; v[1] = (f16)a.y; v[2] = (f16)a.z; v[3] = (f16)a.w;
            v[4] = (f16)b.x; v[5] = (f16)b.y; v[6] = (f16)b.z; v[7] = (f16)b.w;
            *(f16x8*)(smem + ((kc * 64 + r) << 4)) = v;
        }
    }
    {   // prologue: stage B step 0 into buf0 (wave-private slices)
        #pragma unroll
        for (int i = 0; i < 4; ++i)
            gload_lds16((const char*)cbt + i * 4096 + wid * 1024 + (lane << 4),
                        smem + 32768 + i * 4096 + wid * 1024);
    }
    __syncthreads();

    uint32 r1[16], r2[16], r3[16];
    #pragma unroll
    for (int i = 0; i < 16; ++i) { r1[i] = 0xFFFFFFFFu; r2[i] = 0xFFFFFFFFu; r3[i] = 0xFFFFFFFFu; }

    #pragma unroll 1
    for (int ct = 0; ct < 16; ++ct) {
        f32x4 acc[4][4];
        #pragma unroll
        for (int i = 0; i < 4; ++i)
            #pragma unroll
            for (int j = 0; j < 4; ++j) acc[i][j] = (f32x4){0.f, 0.f, 0.f, 0.f};

        #pragma unroll
        for (int kw = 0; kw < 8; ++kw) {
            const int s = ct * 8 + kw;
            asm volatile("s_waitcnt lgkmcnt(0)" ::: "memory");
            __builtin_amdgcn_sched_barrier(0);
            if (kw < 7 || ct < 15) {
                const char* src = (const char*)cbt + (size_t)(s + 1) * 16384;
                char* bufn = smem + 32768 + (((kw + 1) & 1) << 14);
                #pragma unroll
                for (int i = 0; i < 4; ++i)
                    gload_lds16(src + i * 4096 + wid * 1024 + (lane << 4),
                                bufn + i * 4096 + wid * 1024);
                asm volatile("s_waitcnt vmcnt(4)" ::: "memory");
            } else {
                asm volatile("s_waitcnt vmcnt(0)" ::: "memory");
            }
            __builtin_amdgcn_sched_barrier(0);

            const char* bufc = smem + 32768 + ((kw & 1) << 14);
            f16x8 a[4], b[4];
            #pragma unroll
            for (int mi = 0; mi < 4; ++mi)
                a[mi] = *(const f16x8*)(smem + (kw * 4 + g) * 1024 + mi * 256 + (l15 << 4));
            #pragma unroll
            for (int ni = 0; ni < 4; ++ni)
                b[ni] = *(const f16x8*)(bufc + g * 4096 + wid * 1024 + ni * 256 + (l15 << 4));
            // T5: barrier-free loop -> waves at different phases; favor MFMA-entering waves
            __builtin_amdgcn_s_setprio(1);
            #pragma unroll
            for (int mi = 0; mi < 4; ++mi)
                #pragma unroll
                for (int ni = 0; ni < 4; ++ni)
                    acc[mi][ni] = __builtin_amdgcn_mfma_f32_16x16x32_f16(a[mi], b[ni], acc[mi][ni], 0, 0, 0);
            __builtin_amdgcn_s_setprio(0);
        }

        // epilogue: magic-bias keypack + three-smallest tracking (registers only)
        const int cbase = ct * 256 + wid * 64 + l15;
        float c0 = cns[cbase], c1 = cns[cbase + 16], c2 = cns[cbase + 32], c3 = cns[cbase + 48];
        #pragma unroll
        for (int mi = 0; mi < 4; ++mi) {
            #pragma unroll
            for (int r = 0; r < 4; ++r) {
                uint32 k0 = (__float_as_uint(fmaf(-512.f, acc[mi][0][r], c0)) << 12) | (uint32)cbase;
                uint32 k1 = (__float_as_uint(fmaf(-512.f, acc[mi][1][r], c1)) << 12) | (uint32)(cbase + 16);
                uint32 k2 = (__float_as_uint(fmaf(-512.f, acc[mi][2][r], c2)) << 12) | (uint32)(cbase + 32);
                uint32 k3 = (__float_as_uint(fmaf(-512.f, acc[mi][3][r], c3)) << 12) | (uint32)(cbase + 48);
                int q = mi * 4 + r;
                ins3(k0, r1[q], r2[q], r3[q]);
                ins3(k1, r1[q], r2[q], r3[q]);
                ins3(k2, r1[q], r2[q], r3[q]);
                ins3(k3, r1[q], r2[q], r3[q]);
            }
        }
    }

    // butterfly over the 16-lane code group (triples)
    #pragma unroll
    for (int q = 0; q < 16; ++q) {
        uint32 a1 = r1[q], a2 = r2[q], a3 = r3[q];
        #pragma unroll
        for (int m = 1; m < 16; m <<= 1) {
            uint32 o1 = __shfl_xor(a1, m);
            uint32 o2 = __shfl_xor(a2, m);
            uint32 o3 = __shfl_xor(a3, m);
            ins3(o1, a1, a2, a3);
            ins3(o2, a1, a2, a3);
            ins3(o3, a1, a2, a3);
        }
        r1[q] = a1; r2[q] = a2; r3[q] = a3;
    }

    __syncthreads();
    uint4* arr = (uint4*)smem;
    if (l15 == 0) {
        #pragma unroll
        for (int q = 0; q < 16; ++q)
            arr[(wid * 4 + g) * 16 + q] = make_uint4(r1[q], r2[q], r3[q], 0u);
    }
    __syncthreads();
    if (tid < 64) {
        int mi = tid >> 4, gg = (tid >> 2) & 3, r = tid & 3;
        int q = mi * 4 + r;
        uint32 a1 = 0xFFFFFFFFu, a2 = 0xFFFFFFFFu, a3 = 0xFFFFFFFFu;
        #pragma unroll
        for (int w = 0; w < 4; ++w) {
            uint4 v = arr[(w * 4 + gg) * 16 + q];
            ins3(v.x, a1, a2, a3);
            ins3(v.y, a1, a2, a3);
            ins3(v.z, a1, a2, a3);
        }
        int row = row0 + mi * 16 + gg * 4 + r;
        uint32 code1 = a1 & 0xFFFu, code2 = a2 & 0xFFFu;
        uint32 d2 = (a2 >> 12) - (a1 >> 12);
        uint32 d3 = (a3 >> 12) - (a1 >> 12);
        bool full = d3 <= THRQ;
        bool pair = (!full) && (d2 <= THRQ);
        u64 kv = full ? ~0ull
                      : (pair ? (0x8000000000000000ull | ((u64)code2 << 32) | (u64)code1)
                              : (u64)code1);
        keys[row] = kv;
        if (full || pair) {
            int p = atomicAdd(counter, 1);
            list[p] = (uint32)row | (full ? 0x80000000u : 0u);
        }
    }
}

// ---- merged refine: phase 1 = pairwise exact compare, phase 2 = full exact scan ----
__global__ __launch_bounds__(256) void refine_kernel(
    const float* __restrict__ z, const float* __restrict__ cb,
    const float* __restrict__ cnorm, const uint32* __restrict__ list,
    const int* __restrict__ counter, u64* __restrict__ keys)
{
    __shared__ float zs[256];
    const int tid  = threadIdx.x;
    const int lane = tid & 63;
    const int wid  = tid >> 6;
    const int cnt  = *counter;

    // ---- phase 1: pair rows (one wave each) ----
    {
        const int wv = (blockIdx.x << 2) | wid;
        const int nw = gridDim.x << 2;
        for (int i = wv; i < cnt; i += nw) {
            uint32 e = list[i];
            if (e & 0x80000000u) continue;
            int row = (int)e;
            u64 kv = keys[row];
            int c1 = (int)(kv & 0xFFFull);
            int c2 = (int)((kv >> 32) & 0xFFFull);
            float4 zv = *(const float4*)(z + (size_t)row * DDIM + lane * 4);
            float4 av = *(const float4*)(cb + (size_t)c1 * DDIM + lane * 4);
            float4 bv = *(const float4*)(cb + (size_t)c2 * DDIM + lane * 4);
            float d1 = zv.x * av.x + zv.y * av.y + zv.z * av.z + zv.w * av.w;
            float d2 = zv.x * bv.x + zv.y * bv.y + zv.z * bv.z + zv.w * bv.w;
            #pragma unroll
            for (int off = 32; off; off >>= 1) {
                d1 += __shfl_down(d1, off);
                d2 += __shfl_down(d2, off);
            }
            if (lane == 0) {
                float s1 = fmaf(-2.f, d1, cnorm[c1]);
                float s2 = fmaf(-2.f, d2, cnorm[c2]);
                int w = (s2 < s1 || (s2 == s1 && c2 < c1)) ? c2 : c1;
                keys[row] = (u64)w;
            }
        }
    }

    // ---- phase 2: full-scan rows (8 chunk-blocks per row, coalesced) ----
    const int j = lane & 3;
    const int s = lane >> 2;
    for (int w = blockIdx.x; w < cnt * 8; w += gridDim.x) {
        const int i = w >> 3;
        const int chunk = w & 7;
        uint32 e = list[i];
        if (!(e & 0x80000000u)) continue;   // block-uniform
        const int row = (int)(e & 0x7FFFFFFFu);

        __syncthreads();
        zs[tid] = z[(size_t)row * DDIM + tid];
        __syncthreads();

        float4 zr0 = *(const float4*)&zs[s * 16 + 0];
        float4 zr1 = *(const float4*)&zs[s * 16 + 4];
        float4 zr2 = *(const float4*)&zs[s * 16 + 8];
        float4 zr3 = *(const float4*)&zs[s * 16 + 12];

        u64 best = ~0ull;
        const int cstart = chunk * 512 + wid * 128;
        #pragma unroll 2
        for (int c = cstart; c < cstart + 128; c += 4) {
            const float* p = cb + (size_t)(c + j) * DDIM + s * 16;
            float4 q0 = *(const float4*)(p + 0);
            float4 q1 = *(const float4*)(p + 4);
            float4 q2 = *(const float4*)(p + 8);
            float4 q3 = *(const float4*)(p + 12);
            float d = q0.x * zr0.x + q0.y * zr0.y + q0.z * zr0.z + q0.w * zr0.w;
            d = fmaf(q1.x, zr1.x, d); d = fmaf(q1.y, zr1.y, d);
            d = fmaf(q1.z, zr1.z, d); d = fmaf(q1.w, zr1.w, d);
            d = fmaf(q2.x, zr2.x, d); d = fmaf(q2.y, zr2.y, d);
            d = fmaf(q2.z, zr2.z, d); d = fmaf(q2.w, zr2.w, d);
            d = fmaf(q3.x, zr3.x, d); d = fmaf(q3.y, zr3.y, d);
            d = fmaf(q3.z, zr3.z, d); d = fmaf(q3.w, zr3.w, d);
            d += __shfl_xor(d, 4);
            d += __shfl_xor(d, 8);
            d += __shfl_xor(d, 16);
            d += __shfl_xor(d, 32);
            int code = c + j;
            float v = fmaf(-2.f, d, cnorm[code] + 1024.f);
            u64 key = ((u64)__float_as_uint(v) << 12) | (uint32)code;
            u64 o = __shfl_xor(key, 1); key = o < key ? o : key;
            o = __shfl_xor(key, 2); key = o < key ? o : key;
            best = key < best ? key : best;
        }
        if (lane == 0) atomicMin(&keys[row], best);
    }
}

// ---- gather + straight-through + loss partials (R12-proven) ----
__global__ void gather_loss_kernel(const float* __restrict__ z, const float* __restrict__ cb,
                                   const u64* __restrict__ keys, float* __restrict__ out,
                                   float* __restrict__ partials)
{
    const int wave = threadIdx.x >> 6;
    const int lane = threadIdx.x & 63;
    const int row  = blockIdx.x * 4 + wave;
    const int k    = (int)(keys[row] & 0xFFFull);

    const size_t zo = (size_t)row * DDIM + lane * 4;
    float4 zv = *reinterpret_cast<const float4*>(z + zo);
    float4 cv = *reinterpret_cast<const float4*>(cb + (size_t)k * DDIM + lane * 4);
    float4 d;
    d.x = cv.x - zv.x; d.y = cv.y - zv.y; d.z = cv.z - zv.z; d.w = cv.w - zv.w;
    float4 o;
    o.x = zv.x + d.x; o.y = zv.y + d.y; o.z = zv.z + d.z; o.w = zv.w + d.w;
    *reinterpret_cast<float4*>(out + zo) = o;

    float s = d.x * d.x + d.y * d.y + d.z * d.z + d.w * d.w;
    #pragma unroll
    for (int off = 32; off; off >>= 1) s += __shfl_down(s, off);

    __shared__ float ps[4];
    if (lane == 0) ps[wave] = s;
    __syncthreads();
    if (threadIdx.x == 0) partials[blockIdx.x] = (ps[0] + ps[1]) + (ps[2] + ps[3]);
}

__global__ void finalize_kernel(const float* __restrict__ partials, float* __restrict__ out_loss)
{
    float s = 0.f;
    for (int i = threadIdx.x; i < 16384; i += 256) s += partials[i];
    #pragma unroll
    for (int off = 32; off; off >>= 1) s += __shfl_down(s, off);
    __shared__ float ws_[4];
    if ((threadIdx.x & 63) == 0) ws_[threadIdx.x >> 6] = s;
    __syncthreads();
    if (threadIdx.x == 0) {
        float t = (ws_[0] + ws_[1]) + (ws_[2] + ws_[3]);
        float m = t / 16777216.f;
        out_loss[0] = 0.25f * (m + m);
    }
}

// ---- fallback: exact fp32 VALU argmin (known-good R1 path, writes u64 keys) ----
#define BM 128
#define BN 128
#define KC 16
#define LDT 132
__global__ __launch_bounds__(256) void argmin_fallback(
    const float* __restrict__ z, const float* __restrict__ cb,
    const float* __restrict__ cnorm, u64* __restrict__ keys)
{
    __shared__ float As[KC][LDT];
    __shared__ float Bs[KC][LDT];
    const int tid  = threadIdx.x;
    const int tx   = tid & 15;
    const int ty   = tid >> 4;
    const int row0 = blockIdx.x * BM;
    const int srow = tid >> 2;
    const int sg   = (tid & 3) * 4;

    float bestv[8]; int besti[8];
    #pragma unroll
    for (int i = 0; i < 8; ++i) { bestv[i] = 3.402823466e38f; besti[i] = 0; }

    for (int ct = 0; ct < KCODES; ct += BN) {
        float acc[8][8];
        #pragma unroll
        for (int i = 0; i < 8; ++i)
            #pragma unroll
            for (int j = 0; j < 8; ++j) acc[i][j] = 0.f;
        for (int kc = 0; kc < DDIM; kc += KC) {
            __syncthreads();
            {
                const float* za = z  + (size_t)(row0 + srow) * DDIM + kc + sg;
                const float* ba = cb + (size_t)(ct   + srow) * DDIM + kc + sg;
                float4 a0 = *reinterpret_cast<const float4*>(za);
                float4 a1 = *reinterpret_cast<const float4*>(za + (size_t)64 * DDIM);
                float4 b0 = *reinterpret_cast<const float4*>(ba);
                float4 b1 = *reinterpret_cast<const float4*>(ba + (size_t)64 * DDIM);
                As[sg + 0][srow] = a0.x; As[sg + 1][srow] = a0.y; As[sg + 2][srow] = a0.z; As[sg + 3][srow] = a0.w;
                As[sg + 0][srow + 64] = a1.x; As[sg + 1][srow + 64] = a1.y; As[sg + 2][srow + 64] = a1.z; As[sg + 3][srow + 64] = a1.w;
                Bs[sg + 0][srow] = b0.x; Bs[sg + 1][srow] = b0.y; Bs[sg + 2][srow] = b0.z; Bs[sg + 3][srow] = b0.w;
                Bs[sg + 0][srow + 64] = b1.x; Bs[sg + 1][srow + 64] = b1.y; Bs[sg + 2][srow + 64] = b1.z; Bs[sg + 3][srow + 64] = b1.w;
            }
            __syncthreads();
            #pragma unroll
            for (int k = 0; k < KC; ++k) {
                float4 a0 = *reinterpret_cast<const float4*>(&As[k][ty * 8]);
                float4 a1 = *reinterpret_cast<const float4*>(&As[k][ty * 8 + 4]);
                float4 b0 = *reinterpret_cast<const float4*>(&Bs[k][tx * 8]);
                float4 b1 = *reinterpret_cast<const float4*>(&Bs[k][tx * 8 + 4]);
                float av[8] = {a0.x, a0.y, a0.z, a0.w, a1.x, a1.y, a1.z, a1.w};
                float bv[8] = {b0.x, b0.y, b0.z, b0.w, b1.x, b1.y, b1.z, b1.w};
                #pragma unroll
                for (int i = 0; i < 8; ++i)
                    #pragma unroll
                    for (int j = 0; j < 8; ++j)
                        acc[i][j] = fmaf(av[i], bv[j], acc[i][j]);
            }
        }
        float cn[8];
        float4 c0v = *reinterpret_cast<const float4*>(cnorm + ct + tx * 8);
        float4 c1v = *reinterpret_cast<const float4*>(cnorm + ct + tx * 8 + 4);
        cn[0] = c0v.x; cn[1] = c0v.y; cn[2] = c0v.z; cn[3] = c0v.w;
        cn[4] = c1v.x; cn[5] = c1v.y; cn[6] = c1v.z; cn[7] = c1v.w;
        #pragma unroll
        for (int i = 0; i < 8; ++i) {
            float v = fmaf(-2.f, acc[i][0], cn[0]);
            int ix = ct + tx * 8;
            #pragma unroll
            for (int j = 1; j < 8; ++j) {
                float t = fmaf(-2.f, acc[i][j], cn[j]);
                if (t < v) { v = t; ix = ct + tx * 8 + j; }
            }
            #pragma unroll
            for (int m = 1; m < 16; m <<= 1) {
                float ov = __shfl_xor(v, m);
                int oi = __shfl_xor(ix, m);
                if (ov < v || (ov == v && oi < ix)) { v = ov; ix = oi; }
            }
            if (v < bestv[i] || (v == bestv[i] && ix < besti[i])) { bestv[i] = v; besti[i] = ix; }
        }
    }
    if (tx == 0) {
        #pragma unroll
        for (int i = 0; i < 8; ++i) keys[row0 + ty * 8 + i] = (u64)besti[i];
    }
}

extern "C" void kernel_launch(void* const* d_in, const int* in_sizes, int n_in,
                              void* d_out, int out_size, void* d_ws, size_t ws_size,
                              hipStream_t stream)
{
    const float* z  = (const float*)d_in[0];
    const float* cb = (const float*)d_in[1];
    float* out = (float*)d_out;
    char* wsb = (char*)d_ws;

    if (ws_size >= WS_NEEDED) {
        f16*    cbt      = (f16*)(wsb + WS_CBT);
        float*  cnorm    = (float*)(wsb + WS_CNORM);
        float*  cn_s     = (float*)(wsb + WS_CNS);
        u64*    keys     = (u64*)(wsb + WS_KEYS);
        uint32* list     = (uint32*)(wsb + WS_LIST);
        int*    counter  = (int*)(wsb + WS_COUNTER);
        float*  partials = (float*)(wsb + WS_PARTIALS);

        tile_cb_kernel<<<512, 256, 0, stream>>>(cb, cbt, cnorm, cn_s, counter);
        argmin_mfma<<<NROWS / 64, 256, 0, stream>>>(z, cbt, cn_s, keys, list, counter);
        refine_kernel<<<2048, 256, 0, stream>>>(z, cb, cnorm, list, counter, keys);
        gather_loss_kernel<<<NROWS / 4, 256, 0, stream>>>(z, cb, keys, out, partials);
        finalize_kernel<<<1, 256, 0, stream>>>(partials, out + (size_t)NROWS * DDIM);
    } else {
        u64*   keys     = (u64*)(wsb + 0);
        float* cnorm    = (float*)(wsb + 524288);
        float* cn_s     = (float*)(wsb + 540672);
        float* partials = (float*)(wsb + 557056);
        int*   counter  = (int*)(wsb + 622592);

        cnorm_kernel<<<KCODES / 4, 256, 0, stream>>>(cb, cnorm, cn_s, counter);
        argmin_fallback<<<NROWS / BM, 256, 0, stream>>>(z, cb, cnorm, keys);
        gather_loss_kernel<<<NROWS / 4, 256, 0, stream>>>(z, cb, keys, out, partials);
        finalize_kernel<<<1, 256, 0, stream>>>(partials, out + (size_t)NROWS * DDIM);
    }
}